// Round 2
// baseline (1574.279 us; speedup 1.0000x reference)
//
#include <hip/hip_runtime.h>
#include <hip/hip_bf16.h>
#include <math.h>

// B=4, N=512, H=128. out (4,512,512,128) fp32 = 537 MB.
//
// Plan: layer-1 (18->128 + exact GELU) on VALU with wave-uniform W1 slices;
// layer-2 (128x128) on MFMA via split-bf16 (hi/lo, 3-term product, ~1.5e-5 rel).
// Block = 512 thr = 8 waves = one (b,m) row; 8 chunks of 64 pairs (n).
// Thread (wave w, lane l): h[pair=l][hh in 16w..16w+16) -> XOR-swizzled LDS
// (double-buffered, 1 barrier/chunk). Wave w owns out-cols [16w,16w+16):
// W2 hi/lo fragments live in 32 VGPRs for the whole kernel (no LDS B-reads).
// A/B frags both use k = 32*kb + 8*(lane>>4) + e  -> any HW k-permutation
// cancels (A/B symmetric); C/D layout is the m89-verified col=lane&15,
// row=4*(lane>>4)+reg.

#define BB 4
#define NN 512
#define HH 128

typedef __attribute__((ext_vector_type(8))) short bf16x8;
typedef __attribute__((ext_vector_type(4))) float f32x4;

__device__ __forceinline__ unsigned short bf16_rne(float x) {
    unsigned int u = __float_as_uint(x);
    unsigned int r = u + 0x7FFFu + ((u >> 16) & 1u);
    return (unsigned short)(r >> 16);
}

__device__ __forceinline__ float gelu_exact(float x) {
    return 0.5f * x * (1.0f + erff(x * 0.70710678118654752f));
}

__global__ __launch_bounds__(512, 4) void spatial_mlp_mfma(
    const float* __restrict__ bbox_i,  // (B,N,4)
    const float* __restrict__ bbox_j,  // (B,N,4)
    const float* __restrict__ W1,      // (18,H)
    const float* __restrict__ b1,      // (H)
    const float* __restrict__ W2,      // (H,H)
    const float* __restrict__ b2,      // (H)
    float* __restrict__ out)           // (B,N,N,H)
{
    // h tiles, bf16 hi/lo, double buffered: 2*16KB + 2*16KB = 64 KB.
    __shared__ unsigned short Ah[2][64][HH];
    __shared__ unsigned short Al[2][64][HH];

    const int tid  = threadIdx.x;
    const int lane = tid & 63;
    const int w    = tid >> 6;        // wave 0..7 (owns out-cols 16w..16w+16)
    const int g    = lane >> 4;       // k-group 0..3
    const int l15  = lane & 15;

    const int bid   = blockIdx.x;         // b*512 + m
    const int jbase = (bid >> 9) << 9;    // b*512

    // ---- one-time: W2 fragments for this wave's 16 columns, bf16 hi/lo ----
    const int col = (w << 4) + l15;
    bf16x8 bh[4], bl[4];
#pragma unroll
    for (int kb = 0; kb < 4; ++kb) {
#pragma unroll
        for (int e = 0; e < 8; ++e) {
            const float v = W2[(kb * 32 + g * 8 + e) * HH + col];
            const unsigned short hi = bf16_rne(v);
            const float lo = v - __uint_as_float((unsigned int)hi << 16);
            bh[kb][e] = (short)hi;
            bl[kb][e] = (short)bf16_rne(lo);
        }
    }
    const float b2c = b2[col];

    // box i: one box per block
    const float4 bi = *reinterpret_cast<const float4*>(bbox_i + (size_t)bid * 4);
    const float x1i = bi.x, y1i = bi.y, x2i = bi.z, y2i = bi.w;
    const float wi = x2i - x1i, hi_ = y2i - y1i;
    const float cxi = (x1i + x2i) * 0.5f, cyi = (y1i + y2i) * 0.5f;

    // wave-uniform hidden slice base -> forces scalar W1/b1 loads
    const int hh0 = __builtin_amdgcn_readfirstlane(w << 4);

    for (int it = 0; it < 8; ++it) {
        const int buf = it & 1;
        const int n0  = it << 6;

        // ---- features for pair = lane ----
        const float4 bj = *reinterpret_cast<const float4*>(
            bbox_j + (size_t)(jbase + n0 + lane) * 4);
        const float x1j = bj.x, y1j = bj.y, x2j = bj.z, y2j = bj.w;
        const float wj = x2j - x1j, hj = y2j - y1j;
        const float cxj = (x1j + x2j) * 0.5f, cyj = (y1j + y2j) * 0.5f;
        const float dcx = cxj - cxi, dcy = cyj - cyi;

        float f[18];
        f[0]  = dcx;
        f[1]  = dcy;
        f[2]  = x1j - x1i;
        f[3]  = y1j - y1i;
        f[4]  = x2j - x2i;
        f[5]  = y2j - y2i;
        f[6]  = logf((wj + 1.0f) / (wi + 1.0f));
        f[7]  = logf((hj + 1.0f) / (hi_ + 1.0f));
        f[8]  = fmaxf(fminf(x2i, x2j) - fmaxf(x1i, x1j), 0.0f);
        f[9]  = fmaxf(fminf(y2i, y2j) - fmaxf(y1i, y1j), 0.0f);
        f[10] = sqrtf(dcx * dcx + dcy * dcy + 1e-6f);
        f[11] = fabsf(dcx);
        f[12] = fabsf(dcy);
        f[13] = (cxj > cxi) ? 1.0f : 0.0f;
        f[14] = (cyj > cyi) ? 1.0f : 0.0f;
        f[15] = (x1j > x2i) ? 1.0f : 0.0f;
        f[16] = (y1j > y2i) ? 1.0f : 0.0f;
        f[17] = logf((wj * hj + 1.0f) / (wi * hi_ + 1.0f));

        // ---- layer 1: x[e] for hh = hh0+e (scalar W1 ops) ----
        float x[16];
#pragma unroll
        for (int e = 0; e < 16; ++e) x[e] = b1[hh0 + e];
#pragma unroll
        for (int ff = 0; ff < 18; ++ff) {
            const float fv = f[ff];
#pragma unroll
            for (int e = 0; e < 16; ++e)
                x[e] = fmaf(fv, W1[ff * HH + hh0 + e], x[e]);
        }

        // ---- GELU + bf16 hi/lo split, packed two-per-dword ----
        unsigned int hiw[8], low[8];
#pragma unroll
        for (int e2 = 0; e2 < 8; ++e2) {
            const float g0 = gelu_exact(x[2 * e2]);
            const float g1 = gelu_exact(x[2 * e2 + 1]);
            const unsigned int h0 = bf16_rne(g0);
            const unsigned int h1 = bf16_rne(g1);
            const float r0 = g0 - __uint_as_float(h0 << 16);
            const float r1 = g1 - __uint_as_float(h1 << 16);
            hiw[e2] = h0 | ((unsigned int)h1 << 16);
            low[e2] = (unsigned int)bf16_rne(r0) |
                      ((unsigned int)bf16_rne(r1) << 16);
        }

        // ---- LDS write, row = pair = lane, XOR slot swizzle ----
        {
            char* ahp = (char*)Ah + buf * 16384 + lane * 256;
            char* alp = (char*)Al + buf * 16384 + lane * 256;
            const int s0 = ((2 * w + 0) ^ l15) << 4;
            const int s1 = ((2 * w + 1) ^ l15) << 4;
            *reinterpret_cast<uint4*>(ahp + s0) = make_uint4(hiw[0], hiw[1], hiw[2], hiw[3]);
            *reinterpret_cast<uint4*>(ahp + s1) = make_uint4(hiw[4], hiw[5], hiw[6], hiw[7]);
            *reinterpret_cast<uint4*>(alp + s0) = make_uint4(low[0], low[1], low[2], low[3]);
            *reinterpret_cast<uint4*>(alp + s1) = make_uint4(low[4], low[5], low[6], low[7]);
        }

        __syncthreads();

        // ---- layer 2: 4 pair-tiles x 4 k-blocks x 3 split MFMAs ----
        const char* ah_base = (const char*)Ah + buf * 16384;
        const char* al_base = (const char*)Al + buf * 16384;
#pragma unroll
        for (int pt = 0; pt < 4; ++pt) {
            f32x4 acc = {b2c, b2c, b2c, b2c};
            const int row = pt * 16 + l15;
#pragma unroll
            for (int kb = 0; kb < 4; ++kb) {
                const int off = row * 256 + (((kb * 4 + g) ^ l15) << 4);
                const bf16x8 ah = *reinterpret_cast<const bf16x8*>(ah_base + off);
                const bf16x8 al = *reinterpret_cast<const bf16x8*>(al_base + off);
                acc = __builtin_amdgcn_mfma_f32_16x16x32_bf16(ah, bh[kb], acc, 0, 0, 0);
                acc = __builtin_amdgcn_mfma_f32_16x16x32_bf16(ah, bl[kb], acc, 0, 0, 0);
                acc = __builtin_amdgcn_mfma_f32_16x16x32_bf16(al, bh[kb], acc, 0, 0, 0);
            }
            // store: row-in-chunk = 16pt + 4g + r, col = 16w + l15 (m89 C/D map)
            float* o = out + (size_t)(bid * 512 + n0 + pt * 16 + g * 4) * HH + col;
#pragma unroll
            for (int r = 0; r < 4; ++r)
                o[(size_t)r * HH] = acc[r];
        }
        // no second barrier: next iter writes the other buffer (double-buffered)
    }
}

extern "C" void kernel_launch(void* const* d_in, const int* in_sizes, int n_in,
                              void* d_out, int out_size, void* d_ws, size_t ws_size,
                              hipStream_t stream) {
    const float* bbox_i = (const float*)d_in[0];
    const float* bbox_j = (const float*)d_in[1];
    const float* W1     = (const float*)d_in[2];
    const float* b1     = (const float*)d_in[3];
    const float* W2     = (const float*)d_in[4];
    const float* b2     = (const float*)d_in[5];
    float* out = (float*)d_out;

    // one block per (b,m) row: 2048 blocks x 512 threads
    spatial_mlp_mfma<<<BB * NN, 512, 0, stream>>>(bbox_i, bbox_j, W1, b1, W2, b2, out);
}

// Round 6
// 809.922 us; speedup vs baseline: 1.9437x; 1.9437x over previous
//
#include <hip/hip_runtime.h>
#include <hip/hip_bf16.h>
#include <math.h>

// B=4, N=512, H=128. out (4,512,512,128) fp32 = 537 MB.
//
// Layer-1 (18->128 + GELU) on VALU with wave-uniform W1 slices (s_loads);
// layer-2 (128x128) on MFMA via split-bf16 (hi/lo, 3-term, ~2e-4 rel).
// Block = 512 thr = 8 waves = one (b,m) row; 8 chunks of 64 pairs (n).
// R2 fixes vs R1 (which spilled: VGPR=64 cap, consistent with launch_bounds
// arg-2 acting as blocks/CU: 4 blk x 8 waves = 32 waves -> 64 VGPR):
//   - __launch_bounds__(512, 2) -> 16 waves/CU -> 128 VGPR cap, ~110 live fits.
//   - erff -> branch-free A&S 7.1.26 (rcp + 5 FMA + exp2, abs err 1.5e-7)
//   - logf(a/b) -> __logf(a) - __logf(b), i-side hoisted (block-uniform)
//   - sqrtf/rcp via amdgcn builtins (1-instr trans ops)

#define BB 4
#define NN 512
#define HH 128

typedef __attribute__((ext_vector_type(8))) short bf16x8;
typedef __attribute__((ext_vector_type(4))) float f32x4;

__device__ __forceinline__ unsigned short bf16_rne(float x) {
    unsigned int u = __float_as_uint(x);
    unsigned int r = u + 0x7FFFu + ((u >> 16) & 1u);
    return (unsigned short)(r >> 16);
}

// Abramowitz-Stegun 7.1.26: abs err <= 1.5e-7, branch-free.
__device__ __forceinline__ float erf_fast(float x) {
    const float ax = fabsf(x);
    const float t  = __builtin_amdgcn_rcpf(fmaf(0.3275911f, ax, 1.0f));
    float p = fmaf(1.061405429f, t, -1.453152027f);
    p = fmaf(p, t, 1.421413741f);
    p = fmaf(p, t, -0.284496736f);
    p = fmaf(p, t, 0.254829592f);
    p = p * t;
    // exp(-ax^2) = 2^(-ax^2 * log2(e))
    const float e = __builtin_amdgcn_exp2f((ax * -1.44269504088896f) * ax);
    const float r = fmaf(-p, e, 1.0f);
    return copysignf(r, x);
}

__device__ __forceinline__ float gelu_exact(float x) {
    return 0.5f * x * (1.0f + erf_fast(x * 0.70710678118654752f));
}

__global__ __launch_bounds__(512, 2) void spatial_mlp_mfma(
    const float* __restrict__ bbox_i,  // (B,N,4)
    const float* __restrict__ bbox_j,  // (B,N,4)
    const float* __restrict__ W1,      // (18,H)
    const float* __restrict__ b1,      // (H)
    const float* __restrict__ W2,      // (H,H)
    const float* __restrict__ b2,      // (H)
    float* __restrict__ out)           // (B,N,N,H)
{
    // h tiles, bf16 hi/lo, double buffered: 2*16KB + 2*16KB = 64 KB.
    __shared__ unsigned short Ah[2][64][HH];
    __shared__ unsigned short Al[2][64][HH];

    const int tid  = threadIdx.x;
    const int lane = tid & 63;
    const int w    = tid >> 6;        // wave 0..7 (owns out-cols 16w..16w+16)
    const int g    = lane >> 4;       // k-group 0..3
    const int l15  = lane & 15;

    const int bid   = blockIdx.x;         // b*512 + m
    const int jbase = (bid >> 9) << 9;    // b*512

    // ---- one-time: W2 fragments for this wave's 16 columns, bf16 hi/lo ----
    const int col = (w << 4) + l15;
    bf16x8 bh[4], bl[4];
#pragma unroll
    for (int kb = 0; kb < 4; ++kb) {
#pragma unroll
        for (int e = 0; e < 8; ++e) {
            const float v = W2[(kb * 32 + g * 8 + e) * HH + col];
            const unsigned short hi = bf16_rne(v);
            const float lo = v - __uint_as_float((unsigned int)hi << 16);
            bh[kb][e] = (short)hi;
            bl[kb][e] = (short)bf16_rne(lo);
        }
    }
    const float b2c = b2[col];

    // box i: one box per block (block-uniform)
    const float4 bi = *reinterpret_cast<const float4*>(bbox_i + (size_t)bid * 4);
    const float x1i = bi.x, y1i = bi.y, x2i = bi.z, y2i = bi.w;
    const float wi = x2i - x1i, hi_ = y2i - y1i;
    const float cxi = (x1i + x2i) * 0.5f, cyi = (y1i + y2i) * 0.5f;
    // hoisted log terms (block-uniform)
    const float lwi  = __logf(wi + 1.0f);
    const float lhi  = __logf(hi_ + 1.0f);
    const float lahi = __logf(wi * hi_ + 1.0f);

    // wave-uniform hidden slice base -> forces scalar W1/b1 loads
    const int hh0 = __builtin_amdgcn_readfirstlane(w << 4);

    for (int it = 0; it < 8; ++it) {
        const int buf = it & 1;
        const int n0  = it << 6;

        // ---- features for pair = lane ----
        const float4 bj = *reinterpret_cast<const float4*>(
            bbox_j + (size_t)(jbase + n0 + lane) * 4);
        const float x1j = bj.x, y1j = bj.y, x2j = bj.z, y2j = bj.w;
        const float wj = x2j - x1j, hj = y2j - y1j;
        const float cxj = (x1j + x2j) * 0.5f, cyj = (y1j + y2j) * 0.5f;
        const float dcx = cxj - cxi, dcy = cyj - cyi;

        float f[18];
        f[0]  = dcx;
        f[1]  = dcy;
        f[2]  = x1j - x1i;
        f[3]  = y1j - y1i;
        f[4]  = x2j - x2i;
        f[5]  = y2j - y2i;
        f[6]  = __logf(wj + 1.0f) - lwi;
        f[7]  = __logf(hj + 1.0f) - lhi;
        f[8]  = fmaxf(fminf(x2i, x2j) - fmaxf(x1i, x1j), 0.0f);
        f[9]  = fmaxf(fminf(y2i, y2j) - fmaxf(y1i, y1j), 0.0f);
        f[10] = __builtin_amdgcn_sqrtf(fmaf(dcx, dcx, fmaf(dcy, dcy, 1e-6f)));
        f[11] = fabsf(dcx);
        f[12] = fabsf(dcy);
        f[13] = (cxj > cxi) ? 1.0f : 0.0f;
        f[14] = (cyj > cyi) ? 1.0f : 0.0f;
        f[15] = (x1j > x2i) ? 1.0f : 0.0f;
        f[16] = (y1j > y2i) ? 1.0f : 0.0f;
        f[17] = __logf(wj * hj + 1.0f) - lahi;

        // ---- layer 1: x[e] for hh = hh0+e (scalar W1 ops) ----
        float x[16];
#pragma unroll
        for (int e = 0; e < 16; ++e) x[e] = b1[hh0 + e];
#pragma unroll
        for (int ff = 0; ff < 18; ++ff) {
            const float fv = f[ff];
#pragma unroll
            for (int e = 0; e < 16; ++e)
                x[e] = fmaf(fv, W1[ff * HH + hh0 + e], x[e]);
        }

        // ---- GELU + bf16 hi/lo split, packed two-per-dword ----
        unsigned int hiw[8], low[8];
#pragma unroll
        for (int e2 = 0; e2 < 8; ++e2) {
            const float g0 = gelu_exact(x[2 * e2]);
            const float g1 = gelu_exact(x[2 * e2 + 1]);
            const unsigned int h0 = bf16_rne(g0);
            const unsigned int h1 = bf16_rne(g1);
            const float r0 = g0 - __uint_as_float(h0 << 16);
            const float r1 = g1 - __uint_as_float(h1 << 16);
            hiw[e2] = h0 | ((unsigned int)h1 << 16);
            low[e2] = (unsigned int)bf16_rne(r0) |
                      ((unsigned int)bf16_rne(r1) << 16);
        }

        // ---- LDS write, row = pair = lane, XOR slot swizzle ----
        {
            char* ahp = (char*)Ah + buf * 16384 + lane * 256;
            char* alp = (char*)Al + buf * 16384 + lane * 256;
            const int s0 = ((2 * w + 0) ^ l15) << 4;
            const int s1 = ((2 * w + 1) ^ l15) << 4;
            *reinterpret_cast<uint4*>(ahp + s0) = make_uint4(hiw[0], hiw[1], hiw[2], hiw[3]);
            *reinterpret_cast<uint4*>(ahp + s1) = make_uint4(hiw[4], hiw[5], hiw[6], hiw[7]);
            *reinterpret_cast<uint4*>(alp + s0) = make_uint4(low[0], low[1], low[2], low[3]);
            *reinterpret_cast<uint4*>(alp + s1) = make_uint4(low[4], low[5], low[6], low[7]);
        }

        __syncthreads();

        // ---- layer 2: 4 pair-tiles x 4 k-blocks x 3 split MFMAs ----
        const char* ah_base = (const char*)Ah + buf * 16384;
        const char* al_base = (const char*)Al + buf * 16384;
#pragma unroll
        for (int pt = 0; pt < 4; ++pt) {
            f32x4 acc = {b2c, b2c, b2c, b2c};
            const int row = pt * 16 + l15;
#pragma unroll
            for (int kb = 0; kb < 4; ++kb) {
                const int off = row * 256 + (((kb * 4 + g) ^ l15) << 4);
                const bf16x8 ah = *reinterpret_cast<const bf16x8*>(ah_base + off);
                const bf16x8 al = *reinterpret_cast<const bf16x8*>(al_base + off);
                acc = __builtin_amdgcn_mfma_f32_16x16x32_bf16(ah, bh[kb], acc, 0, 0, 0);
                acc = __builtin_amdgcn_mfma_f32_16x16x32_bf16(ah, bl[kb], acc, 0, 0, 0);
                acc = __builtin_amdgcn_mfma_f32_16x16x32_bf16(al, bh[kb], acc, 0, 0, 0);
            }
            // store: row-in-chunk = 16pt + 4g + r, col = 16w + l15 (m89 C/D map)
            float* o = out + (size_t)(bid * 512 + n0 + pt * 16 + g * 4) * HH + col;
#pragma unroll
            for (int r = 0; r < 4; ++r)
                o[(size_t)r * HH] = acc[r];
        }
        // no second barrier needed for next write: double-buffered
    }
}

extern "C" void kernel_launch(void* const* d_in, const int* in_sizes, int n_in,
                              void* d_out, int out_size, void* d_ws, size_t ws_size,
                              hipStream_t stream) {
    const float* bbox_i = (const float*)d_in[0];
    const float* bbox_j = (const float*)d_in[1];
    const float* W1     = (const float*)d_in[2];
    const float* b1     = (const float*)d_in[3];
    const float* W2     = (const float*)d_in[4];
    const float* b2     = (const float*)d_in[5];
    float* out = (float*)d_out;

    // one block per (b,m) row: 2048 blocks x 512 threads
    spatial_mlp_mfma<<<BB * NN, 512, 0, stream>>>(bbox_i, bbox_j, W1, b1, W2, b2, out);
}